// Round 1
// baseline (1190.229 us; speedup 1.0000x reference)
//
#include <hip/hip_runtime.h>
#include <math.h>

constexpr int MCO = 9;     // spherical coefficients (lmax=2)
constexpr int CC  = 128;   // channels
constexpr int HD  = 128;   // hidden
constexpr int AA  = 42;    // grid points
constexpr int AT  = 14;    // a-tile size
constexpr int NTI = 3;     // number of a-tiles (42 = 3*14)
constexpr int NPW = 2;     // nodes per workgroup
constexpr int MC  = MCO * CC;  // 1152

__device__ __forceinline__ float dot4(float4 a, float4 b) {
    return a.x*b.x + a.y*b.y + a.z*b.z + a.w*b.w;
}

// DIM consecutive dot-products (length 128) against one streamed weight row.
// srcbase: LDS base of [MCO][128] activations; wrow: global weight row ptr.
template<int DIM>
__device__ __forceinline__ void lin_block(const float* __restrict__ wrow,
                                          const float* __restrict__ srcbase,
                                          int m0, float* __restrict__ acc)
{
    const float4* wr = (const float4*)wrow;
    #pragma unroll
    for (int d = 0; d < DIM; ++d) acc[d] = 0.f;
    #pragma unroll 8
    for (int k = 0; k < CC/4; ++k) {
        const float4 w4 = wr[k];
        #pragma unroll
        for (int d = 0; d < DIM; ++d) {
            const float4 p4 = ((const float4*)(srcbase + (size_t)(m0+d)*CC))[k];
            acc[d] += dot4(p4, w4);
        }
    }
}

__global__ __launch_bounds__(256) void eqffn_kernel(
    const float* __restrict__ x,    // [N,1152]
    const float* __restrict__ nw,   // [3,128]
    const float* __restrict__ w1,   // [3,H,C]
    const float* __restrict__ b1,   // [H]
    const float* __restrict__ gw,   // [2H,H]
    const float* __restrict__ gb,   // [2H]
    const float* __restrict__ w2,   // [3,C,H]
    const float* __restrict__ b2,   // [C]
    const float* __restrict__ tg,   // [A,M]
    const float* __restrict__ fg,   // [M,A]
    float* __restrict__ out,        // [N,1152]
    int N)
{
    __shared__ __align__(16) float sh_p [NPW][MCO][CC];
    __shared__ __align__(16) float sh_h1[NPW][MCO][HD];
    __shared__ __align__(16) float sh_g [NPW][AT][HD];
    __shared__ __align__(16) float sh_h2[NPW][MCO][HD];
    __shared__ float sh_tg[AA*MCO];
    __shared__ float sh_fg[MCO*AA];
    __shared__ float sh_nw[3*CC];
    __shared__ float sh_red[4];

    const int tid = threadIdx.x;
    const int s   = tid >> 7;       // node slot within WG
    const int hh  = tid & 127;      // channel / hidden index
    const int n   = blockIdx.x * NPW + s;
    const bool valid = (n < N);

    // small tables -> LDS
    for (int i = tid; i < AA*MCO; i += 256) sh_tg[i] = tg[i];
    for (int i = tid; i < MCO*AA; i += 256) sh_fg[i] = fg[i];
    for (int i = tid; i < 3*CC;   i += 256) sh_nw[i] = nw[i];

    // ---- pack (analytic permutation) + sum of squares ----
    float pv[MCO];
    float ss = 0.f;
    if (valid) {
        const float* xr = x + (size_t)n * MC;
        pv[0] = xr[hh];                                   // l=0
        #pragma unroll
        for (int d = 0; d < 3; ++d) pv[1+d] = xr[128 + hh*3 + d];  // l=1
        #pragma unroll
        for (int d = 0; d < 5; ++d) pv[4+d] = xr[512 + hh*5 + d];  // l=2
        #pragma unroll
        for (int m = 0; m < MCO; ++m) ss += pv[m]*pv[m];
    }
    // wave reduce (64 lanes), then combine 2 waves per node
    #pragma unroll
    for (int off = 32; off; off >>= 1) ss += __shfl_xor(ss, off);
    if ((tid & 63) == 0) sh_red[tid >> 6] = ss;
    __syncthreads();

    const float tot = sh_red[2*s] + sh_red[2*s+1];
    const float inv = 1.0f / sqrtf(tot * (1.0f/(float)MC) + 1e-6f);

    if (valid) {
        #pragma unroll
        for (int m = 0; m < MCO; ++m) {
            const int l = (m == 0) ? 0 : ((m < 4) ? 1 : 2);
            sh_p[s][m][hh] = pv[m] * inv * sh_nw[l*CC + hh];
        }
    }
    __syncthreads();

    // ---- Linear1: h1[m,h] = sum_c p[m,c] * w1[l][h,c]  (+b1 on m=0) ----
    {
        float a0[1], a1[3], a2[5];
        const float* pb = &sh_p[s][0][0];
        lin_block<1>(w1 + (size_t)(0*HD + hh)*CC, pb, 0, a0);
        lin_block<3>(w1 + (size_t)(1*HD + hh)*CC, pb, 1, a1);
        lin_block<5>(w1 + (size_t)(2*HD + hh)*CC, pb, 4, a2);
        sh_h1[s][0][hh] = a0[0] + b1[hh];
        #pragma unroll
        for (int d = 0; d < 3; ++d) sh_h1[s][1+d][hh] = a1[d];
        #pragma unroll
        for (int d = 0; d < 5; ++d) sh_h1[s][4+d][hh] = a2[d];
    }
    // zero h2 accumulator (owner-only, no barrier needed for it)
    #pragma unroll
    for (int m = 0; m < MCO; ++m) sh_h2[s][m][hh] = 0.f;
    __syncthreads();

    const float gblo = gb[hh], gbhi = gb[CC + hh];

    // ---- a-tiled: to_grid -> SwiGLU GEMM -> from_grid accumulate ----
    for (int t = 0; t < NTI; ++t) {
        #pragma unroll
        for (int al = 0; al < AT; ++al) {
            const int a = t*AT + al;
            float acc = 0.f;
            #pragma unroll
            for (int m = 0; m < MCO; ++m) acc += sh_tg[a*MCO + m] * sh_h1[s][m][hh];
            sh_g[s][al][hh] = acc;
        }
        __syncthreads();

        float acclo[AT], acchi[AT];
        #pragma unroll
        for (int al = 0; al < AT; ++al) { acclo[al] = 0.f; acchi[al] = 0.f; }
        const float4* wlo = (const float4*)(gw + (size_t)hh*HD);
        const float4* whi = (const float4*)(gw + (size_t)(CC + hh)*HD);
        const float4* gbase = (const float4*)&sh_g[s][0][0];
        #pragma unroll 4
        for (int k = 0; k < HD/4; ++k) {
            const float4 w4l = wlo[k];
            const float4 w4h = whi[k];
            #pragma unroll
            for (int al = 0; al < AT; ++al) {
                const float4 g4 = gbase[al*(HD/4) + k];   // same-address broadcast
                acclo[al] += dot4(g4, w4l);
                acchi[al] += dot4(g4, w4h);
            }
        }
        __syncthreads();   // all sh_g reads done before overwrite
        #pragma unroll
        for (int al = 0; al < AT; ++al) {
            const float zl = acclo[al] + gblo;
            const float zh = acchi[al] + gbhi;
            const float sig = 1.0f / (1.0f + __expf(-zl));
            sh_g[s][al][hh] = zl * sig * zh;   // silu(zl) * zh
        }
        __syncthreads();
        #pragma unroll
        for (int m = 0; m < MCO; ++m) {
            float acc = sh_h2[s][m][hh];
            #pragma unroll
            for (int al = 0; al < AT; ++al)
                acc += sh_fg[m*AA + t*AT + al] * sh_g[s][al][hh];
            sh_h2[s][m][hh] = acc;
        }
        __syncthreads();   // before next tile overwrites sh_g; also covers Linear2
    }

    // ---- Linear2 + bias + unpack scatter write ----
    if (valid) {
        float* orow = out + (size_t)n * MC;
        float a0[1], a1[3], a2[5];
        const float* hb = &sh_h2[s][0][0];
        lin_block<1>(w2 + (size_t)(0*CC + hh)*HD, hb, 0, a0);
        lin_block<3>(w2 + (size_t)(1*CC + hh)*HD, hb, 1, a1);
        lin_block<5>(w2 + (size_t)(2*CC + hh)*HD, hb, 4, a2);
        orow[hh] = a0[0] + b2[hh];
        #pragma unroll
        for (int d = 0; d < 3; ++d) orow[128 + hh*3 + d] = a1[d];
        #pragma unroll
        for (int d = 0; d < 5; ++d) orow[512 + hh*5 + d] = a2[d];
    }
}

extern "C" void kernel_launch(void* const* d_in, const int* in_sizes, int n_in,
                              void* d_out, int out_size, void* d_ws, size_t ws_size,
                              hipStream_t stream)
{
    const float* x  = (const float*)d_in[0];
    const float* nw = (const float*)d_in[1];
    const float* w1 = (const float*)d_in[2];
    const float* b1 = (const float*)d_in[3];
    const float* gw = (const float*)d_in[4];
    const float* gb = (const float*)d_in[5];
    const float* w2 = (const float*)d_in[6];
    const float* b2 = (const float*)d_in[7];
    const float* tg = (const float*)d_in[8];
    const float* fg = (const float*)d_in[9];
    float* out = (float*)d_out;

    const int N = in_sizes[0] / MC;
    const int blocks = (N + NPW - 1) / NPW;
    eqffn_kernel<<<blocks, 256, 0, stream>>>(x, nw, w1, b1, gw, gb, w2, b2, tg, fg, out, N);
}

// Round 2
// 256.907 us; speedup vs baseline: 4.6329x; 4.6329x over previous
//
#include <hip/hip_runtime.h>
#include <math.h>

typedef unsigned short u16;
typedef __attribute__((ext_vector_type(8))) short bf16x8;
typedef __attribute__((ext_vector_type(4))) float f32x4;
typedef __attribute__((ext_vector_type(16))) float f32x16;

// workspace layout (bf16 elements)
constexpr int OFF_W1 = 0;          // [3][128][128]  (l, h, c)
constexpr int OFF_W2 = 49152;      // [3][128][128]  (l, c, h)
constexpr int OFF_GW = 98304;      // [256][128]     (o, h)
constexpr int OFF_TG = 131072;     // [64][16]  rows>=42 / cols>=9 zero
constexpr int OFF_FG = 132096;     // [32][64]  rows>=9  / cols>=42 zero
constexpr int WS_ELEMS = 134144;   // 268288 bytes needed in d_ws

__device__ __forceinline__ u16 f2bf(float f) {
    unsigned u = __float_as_uint(f);
    u += 0x7FFFu + ((u >> 16) & 1u);   // RNE
    return (u16)(u >> 16);
}

__global__ void prep_kernel(const float* __restrict__ w1, const float* __restrict__ gw,
                            const float* __restrict__ w2, const float* __restrict__ tg,
                            const float* __restrict__ fg, u16* __restrict__ wsb) {
    const int idx = blockIdx.x * blockDim.x + threadIdx.x;
    const int str = gridDim.x * blockDim.x;
    for (int i = idx; i < 49152; i += str) wsb[OFF_W1 + i] = f2bf(w1[i]);
    for (int i = idx; i < 49152; i += str) wsb[OFF_W2 + i] = f2bf(w2[i]);
    for (int i = idx; i < 32768; i += str) wsb[OFF_GW + i] = f2bf(gw[i]);
    for (int i = idx; i < 1024; i += str) {
        int a = i >> 4, k = i & 15;
        wsb[OFF_TG + i] = (a < 42 && k < 9) ? f2bf(tg[a * 9 + k]) : (u16)0;
    }
    for (int i = idx; i < 2048; i += str) {
        int m = i >> 6, k = i & 63;
        wsb[OFF_FG + i] = (m < 9 && k < 42) ? f2bf(fg[m * 42 + k]) : (u16)0;
    }
}

// 4 nodes per 256-thread WG.  LDS ~67 KB -> 2 WG/CU.
// batched-row layout (64 rows): l0: rows 0..3 (node), l1: 16+n*3+mm, l2: 32+n*5+mm
__global__ __launch_bounds__(256, 2) void eqffn_mfma(
    const float* __restrict__ x, const float* __restrict__ nw,
    const float* __restrict__ b1f, const float* __restrict__ gbf,
    const float* __restrict__ b2f, const u16* __restrict__ wsb,
    float* __restrict__ out, int N)
{
    __shared__ u16 sh_a1[64 * 136];       // A1 (packed norm acts), later h2b (union)
    __shared__ u16 sh_h1T[4 * 128 * 16];  // per node: [h][m-pad16], pad cols zero
    __shared__ u16 sh_g[48 * 136];        // per-node grid acts [a][h]
    __shared__ u16 sh_g2T[128 * 72];      // per-node swiglu out [o][a-pad], pad cols zero
    __shared__ float sh_nw[384];
    __shared__ float sh_b1[128];
    __shared__ float sh_b2[128];
    __shared__ float sh_gb[256];

    const int tid  = threadIdx.x;
    const int w    = tid >> 6;       // wave id
    const int lane = tid & 63;
    const int q    = lane >> 4;      // 16x16 quad
    const int r    = lane & 15;
    const int r32  = lane & 31;      // 32x32 row/col
    const int half = lane >> 5;
    const int n0   = blockIdx.x * 4;

    // ---- init: stage small vectors, zero padded LDS regions ----
    for (int i = tid; i < 384; i += 256) sh_nw[i] = nw[i];
    if (tid < 128) { sh_b1[tid] = b1f[tid]; sh_b2[tid] = b2f[tid]; }
    sh_gb[tid] = gbf[tid];
    {
        unsigned long long* z1 = (unsigned long long*)sh_h1T;
        for (int i = tid; i < 2048; i += 256) z1[i] = 0ull;
        unsigned long long* z2 = (unsigned long long*)sh_g2T;
        for (int i = tid; i < 2304; i += 256) z2[i] = 0ull;
    }
    __syncthreads();

    // ---- phase A: load x (wave w -> node n0+w), RMS, pack+normalize -> A1 bf16 ----
    const int myn = n0 + w;
    float4 xv[5];
    float ss = 0.f;
    if (myn < N) {
        const float4* xr = (const float4*)(x + (size_t)myn * 1152);
        for (int i = lane, c2 = 0; i < 288; i += 64, ++c2) {
            float4 v = xr[i]; xv[c2] = v;
            ss += v.x * v.x + v.y * v.y + v.z * v.z + v.w * v.w;
        }
    }
    #pragma unroll
    for (int off = 32; off; off >>= 1) ss += __shfl_xor(ss, off);
    const float inv = 1.0f / sqrtf(ss * (1.0f / 1152.0f) + 1e-6f);
    if (myn < N) {
        for (int i = lane, c2 = 0; i < 288; i += 64, ++c2) {
            float4 v = xv[c2];
            #pragma unroll
            for (int e = 0; e < 4; ++e) {
                const int f = i * 4 + e;
                const float val = ((const float*)&v)[e] * inv;
                int row, c, l;
                if (f < 128)      { l = 0; c = f;            row = w; }
                else if (f < 512) { int t = f - 128; l = 1; c = t / 3; row = 16 + w * 3 + (t - c * 3); }
                else              { int t = f - 512; l = 2; c = t / 5; row = 32 + w * 5 + (t - c * 5); }
                sh_a1[row * 136 + c] = f2bf(val * sh_nw[l * 128 + c]);
            }
        }
    }
    __syncthreads();

    // ---- GEMM1 (batched, 16x16x32): h1[row][h] = sum_c A1[row][c] w1[l][h][c] ----
    {
        f32x4 acc[4][2];
        #pragma unroll
        for (int a = 0; a < 4; ++a)
            #pragma unroll
            for (int b = 0; b < 2; ++b)
                #pragma unroll
                for (int e = 0; e < 4; ++e) acc[a][b][e] = 0.f;
        #pragma unroll
        for (int mt = 0; mt < 4; ++mt) {
            const int l = (mt == 0) ? 0 : ((mt == 1) ? 1 : 2);
            #pragma unroll
            for (int k = 0; k < 4; ++k) {
                bf16x8 af = *(const bf16x8*)&sh_a1[(mt * 16 + r) * 136 + k * 32 + q * 8];
                #pragma unroll
                for (int nt = 0; nt < 2; ++nt) {
                    const int h = (2 * w + nt) * 16 + r;
                    bf16x8 bf = *(const bf16x8*)&wsb[OFF_W1 + (l * 128 + h) * 128 + k * 32 + q * 8];
                    acc[mt][nt] = __builtin_amdgcn_mfma_f32_16x16x32_bf16(af, bf, acc[mt][nt], 0, 0, 0);
                }
            }
        }
        // epilogue: +b1 on l0, write h1T[node][h][m]
        #pragma unroll
        for (int mt = 0; mt < 4; ++mt) {
            #pragma unroll
            for (int nt = 0; nt < 2; ++nt) {
                const int h = (2 * w + nt) * 16 + r;
                #pragma unroll
                for (int rg = 0; rg < 4; ++rg) {
                    const int rr = q * 4 + rg;
                    const float v = acc[mt][nt][rg];
                    if (mt == 0) {
                        if (rr < 4) sh_h1T[(rr * 128 + h) * 16 + 0] = f2bf(v + sh_b1[h]);
                    } else if (mt == 1) {
                        if (rr < 12) { int nd = rr / 3, mm = rr - nd * 3; sh_h1T[(nd * 128 + h) * 16 + 1 + mm] = f2bf(v); }
                    } else {
                        int rr2 = (mt - 2) * 16 + rr;
                        if (rr2 < 20) { int nd = rr2 / 5, mm = rr2 - nd * 5; sh_h1T[(nd * 128 + h) * 16 + 4 + mm] = f2bf(v); }
                    }
                }
            }
        }
    }
    __syncthreads();

    // ---- per-node grid pipeline ----
    for (int nn = 0; nn < 4; ++nn) {
        // to_grid (32x32x16): g[a][h] = sum_m tg[a][m] h1[nn][m][h]; wave w -> h block w*32
        {
            bf16x8 bfr = *(const bf16x8*)&sh_h1T[(nn * 128 + w * 32 + r32) * 16 + half * 8];
            bf16x8 a0  = *(const bf16x8*)&wsb[OFF_TG + r32 * 16 + half * 8];
            bf16x8 a1  = *(const bf16x8*)&wsb[OFF_TG + (32 + r32) * 16 + half * 8];
            f32x16 ac0, ac1;
            #pragma unroll
            for (int e = 0; e < 16; ++e) { ac0[e] = 0.f; ac1[e] = 0.f; }
            ac0 = __builtin_amdgcn_mfma_f32_32x32x16_bf16(a0, bfr, ac0, 0, 0, 0);
            ac1 = __builtin_amdgcn_mfma_f32_32x32x16_bf16(a1, bfr, ac1, 0, 0, 0);
            const int h = w * 32 + r32;
            #pragma unroll
            for (int rg = 0; rg < 16; ++rg) {
                const int ar = (rg & 3) + 8 * (rg >> 2) + 4 * half;
                sh_g[ar * 136 + h] = f2bf(ac0[rg]);
                const int ar1 = 32 + ar;
                if (ar1 < 48) sh_g[ar1 * 136 + h] = f2bf(ac1[rg]);
            }
        }
        __syncthreads();   // g ready (also: g2T free for rewrite)

        // SwiGLU (transposed, 16x16x32): zT[o][a] = sum_h gw[o][h] g[a][h]
        {
            bf16x8 bfr[3][4];
            #pragma unroll
            for (int nt = 0; nt < 3; ++nt)
                #pragma unroll
                for (int k = 0; k < 4; ++k)
                    bfr[nt][k] = *(const bf16x8*)&sh_g[(nt * 16 + r) * 136 + k * 32 + q * 8];
            f32x4 aL[2][3], aH[2][3];
            #pragma unroll
            for (int p = 0; p < 2; ++p)
                #pragma unroll
                for (int nt = 0; nt < 3; ++nt)
                    #pragma unroll
                    for (int e = 0; e < 4; ++e) { aL[p][nt][e] = 0.f; aH[p][nt][e] = 0.f; }
            #pragma unroll
            for (int p = 0; p < 2; ++p) {
                const int oL = (2 * w + p) * 16 + r;
                const int oH = oL + 128;
                #pragma unroll
                for (int k = 0; k < 4; ++k) {
                    bf16x8 fL = *(const bf16x8*)&wsb[OFF_GW + oL * 128 + k * 32 + q * 8];
                    bf16x8 fH = *(const bf16x8*)&wsb[OFF_GW + oH * 128 + k * 32 + q * 8];
                    #pragma unroll
                    for (int nt = 0; nt < 3; ++nt) {
                        aL[p][nt] = __builtin_amdgcn_mfma_f32_16x16x32_bf16(fL, bfr[nt][k], aL[p][nt], 0, 0, 0);
                        aH[p][nt] = __builtin_amdgcn_mfma_f32_16x16x32_bf16(fH, bfr[nt][k], aH[p][nt], 0, 0, 0);
                    }
                }
            }
            // silu epilogue -> g2T[o][a]
            #pragma unroll
            for (int p = 0; p < 2; ++p) {
                #pragma unroll
                for (int nt = 0; nt < 3; ++nt) {
                    #pragma unroll
                    for (int rg = 0; rg < 4; ++rg) {
                        const int o = (2 * w + p) * 16 + q * 4 + rg;
                        const int a = nt * 16 + r;
                        const float zl = aL[p][nt][rg] + sh_gb[o];
                        const float zh = aH[p][nt][rg] + sh_gb[128 + o];
                        const float gv = zl * (1.0f / (1.0f + __expf(-zl))) * zh;
                        if (a < 42) sh_g2T[o * 72 + a] = f2bf(gv);
                    }
                }
            }
        }
        __syncthreads();   // g2T ready

        // from_grid (32x32x16, K=64): h2[m][h] = sum_a fg[m][a] g2T[h][a] -> h2b (sh_a1)
        {
            f32x16 ac;
            #pragma unroll
            for (int e = 0; e < 16; ++e) ac[e] = 0.f;
            const int h = w * 32 + r32;
            #pragma unroll
            for (int k = 0; k < 4; ++k) {
                bf16x8 af = *(const bf16x8*)&wsb[OFF_FG + r32 * 64 + k * 16 + half * 8];
                bf16x8 bf = *(const bf16x8*)&sh_g2T[h * 72 + k * 16 + half * 8];
                ac = __builtin_amdgcn_mfma_f32_32x32x16_bf16(af, bf, ac, 0, 0, 0);
            }
            #pragma unroll
            for (int rg = 0; rg < 16; ++rg) {
                const int m = (rg & 3) + 8 * (rg >> 2) + 4 * half;
                if (m < 9) {
                    const int row = (m == 0) ? nn : ((m < 4) ? (16 + nn * 3 + (m - 1)) : (32 + nn * 5 + (m - 4)));
                    sh_a1[row * 136 + h] = f2bf(ac[rg]);
                }
            }
        }
        // next to_grid writes sh_g (disjoint); bar after to_grid orders g2T rewrite
    }
    __syncthreads();

    // ---- GEMM2 (batched, 16x16x32) + bias + unpack scatter store ----
    {
        f32x4 acc[4][2];
        #pragma unroll
        for (int a = 0; a < 4; ++a)
            #pragma unroll
            for (int b = 0; b < 2; ++b)
                #pragma unroll
                for (int e = 0; e < 4; ++e) acc[a][b][e] = 0.f;
        #pragma unroll
        for (int mt = 0; mt < 4; ++mt) {
            const int l = (mt == 0) ? 0 : ((mt == 1) ? 1 : 2);
            #pragma unroll
            for (int k = 0; k < 4; ++k) {
                bf16x8 af = *(const bf16x8*)&sh_a1[(mt * 16 + r) * 136 + k * 32 + q * 8];
                #pragma unroll
                for (int nt = 0; nt < 2; ++nt) {
                    const int c = (2 * w + nt) * 16 + r;
                    bf16x8 bf = *(const bf16x8*)&wsb[OFF_W2 + (l * 128 + c) * 128 + k * 32 + q * 8];
                    acc[mt][nt] = __builtin_amdgcn_mfma_f32_16x16x32_bf16(af, bf, acc[mt][nt], 0, 0, 0);
                }
            }
        }
        #pragma unroll
        for (int mt = 0; mt < 4; ++mt) {
            #pragma unroll
            for (int nt = 0; nt < 2; ++nt) {
                const int c = (2 * w + nt) * 16 + r;
                #pragma unroll
                for (int rg = 0; rg < 4; ++rg) {
                    const int rr = q * 4 + rg;
                    const float v = acc[mt][nt][rg];
                    if (mt == 0) {
                        if (rr < 4) { int gn = n0 + rr; if (gn < N) out[(size_t)gn * 1152 + c] = v + sh_b2[c]; }
                    } else if (mt == 1) {
                        if (rr < 12) { int nd = rr / 3, mm = rr - nd * 3; int gn = n0 + nd;
                                       if (gn < N) out[(size_t)gn * 1152 + 128 + c * 3 + mm] = v; }
                    } else {
                        int rr2 = (mt - 2) * 16 + rr;
                        if (rr2 < 20) { int nd = rr2 / 5, mm = rr2 - nd * 5; int gn = n0 + nd;
                                        if (gn < N) out[(size_t)gn * 1152 + 512 + c * 5 + mm] = v; }
                    }
                }
            }
        }
    }
}

extern "C" void kernel_launch(void* const* d_in, const int* in_sizes, int n_in,
                              void* d_out, int out_size, void* d_ws, size_t ws_size,
                              hipStream_t stream)
{
    const float* x  = (const float*)d_in[0];
    const float* nw = (const float*)d_in[1];
    const float* w1 = (const float*)d_in[2];
    const float* b1 = (const float*)d_in[3];
    const float* gw = (const float*)d_in[4];
    const float* gb = (const float*)d_in[5];
    const float* w2 = (const float*)d_in[6];
    const float* b2 = (const float*)d_in[7];
    const float* tg = (const float*)d_in[8];
    const float* fg = (const float*)d_in[9];
    float* out = (float*)d_out;
    u16* wsb = (u16*)d_ws;

    const int N = in_sizes[0] / 1152;
    prep_kernel<<<64, 256, 0, stream>>>(w1, gw, w2, tg, fg, wsb);
    eqffn_mfma<<<(N + 3) / 4, 256, 0, stream>>>(x, nw, b1, gb, b2, wsb, out, N);
}